// Round 4
// baseline (385.142 us; speedup 1.0000x reference)
//
#include <hip/hip_runtime.h>
#include <hip/hip_cooperative_groups.h>
#include <math.h>

namespace cg = cooperative_groups;

#define N 16384
#define MD 512
#define CTRLDIM 1024
#define OUTF 1542   // 3*512+6
#define NBLK 1024
#define NTHR 256

// ws layout (floats):
//   [0    .. 1541]   O      projection output o
//   [1552 .. 2063]   E      erase vec (16B-aligned)
//   [2064 .. 2575]   A      add vec (16B-aligned)
//   [2576 .. 3599]   PART1  per-block partial sums of exp (1024 blocks)
//   [3600 .. 3663]   PART2  per-block partial sums of wp (64 active blocks)
//   [3664 .. 20047]  EZ     exp(beta*sim - beta) per row
//   [20048.. 36431]  WP     (ws+eps)^gamma per row

__device__ __forceinline__ float softplus_f(float x) {
    return (x > 20.f) ? x : log1pf(expf(x));
}

__device__ __forceinline__ float wave_bfly_sum(float v) {
    #pragma unroll
    for (int off = 1; off < 64; off <<= 1) v += __shfl_xor(v, off, 64);
    return v;
}

// One cooperative kernel: proj -> [sync] -> sim -> [sync] -> shift -> [sync] -> update.
// 1024 blocks x 256 thr, <=128 VGPR (launch_bounds 256,4) => 4 blocks/CU co-resident.
__global__ void __launch_bounds__(NTHR, 4) k_fused(
        const float* __restrict__ emb, const float* __restrict__ wprev,
        const float* __restrict__ mem, const float* __restrict__ W,
        const float* __restrict__ b, float* __restrict__ wout,
        float* __restrict__ outMem, float* __restrict__ wsf) {
    cg::grid_group grid = cg::this_grid();
    float* O     = wsf;
    float* E     = wsf + 1552;
    float* A     = wsf + 2064;
    float* PART1 = wsf + 2576;
    float* PART2 = wsf + 3600;
    float* EZ    = wsf + 3664;
    float* WP    = wsf + 20048;

    int t = threadIdx.x, lane = t & 63, wid = t >> 6;
    __shared__ float sblk[4];

    // ---- Phase A: o[row] = dot(W[row], emb) + b[row]; scatter E/A ----
    for (int row = blockIdx.x; row < OUTF; row += NBLK) {
        const float4* w4 = (const float4*)(W + (size_t)row * CTRLDIM);
        const float4* e4 = (const float4*)emb;
        float4 wv = w4[t];
        float4 ev = e4[t];
        float p = wv.x * ev.x + wv.y * ev.y + wv.z * ev.z + wv.w * ev.w;
        p = wave_bfly_sum(p);
        if (lane == 0) sblk[wid] = p;
        __syncthreads();
        if (t == 0) {
            float val = sblk[0] + sblk[1] + sblk[2] + sblk[3] + b[row];
            O[row] = val;
            if (row >= MD + 6 && row < 2 * MD + 6)  E[row - (MD + 6)] = val;
            else if (row >= 2 * MD + 6)             A[row - (2 * MD + 6)] = val;
        }
        __syncthreads();
    }
    grid.sync();

    // ---- Phase B: EZ[row] = exp(beta*sim - beta); PART1[block] ----
    {
        const float4* k4 = (const float4*)O;
        float4 k0 = k4[lane], k1 = k4[lane + 64];
        float ksq = k0.x * k0.x + k0.y * k0.y + k0.z * k0.z + k0.w * k0.w
                  + k1.x * k1.x + k1.y * k1.y + k1.z * k1.z + k1.w * k1.w;
        ksq = wave_bfly_sum(ksq);
        float knorm = sqrtf(ksq);
        float beta = softplus_f(O[MD]);
        int row0 = (blockIdx.x * 4 + wid) * 4;
        float4 m0[4], m1[4];
        #pragma unroll
        for (int r = 0; r < 4; r++) {
            const float4* m4 = (const float4*)(mem + (size_t)(row0 + r) * MD);
            m0[r] = m4[lane];
            m1[r] = m4[lane + 64];
        }
        float wsum = 0.f;
        #pragma unroll
        for (int r = 0; r < 4; r++) {
            float dot = m0[r].x * k0.x + m0[r].y * k0.y + m0[r].z * k0.z + m0[r].w * k0.w
                      + m1[r].x * k1.x + m1[r].y * k1.y + m1[r].z * k1.z + m1[r].w * k1.w;
            float nsq = m0[r].x * m0[r].x + m0[r].y * m0[r].y + m0[r].z * m0[r].z + m0[r].w * m0[r].w
                      + m1[r].x * m1[r].x + m1[r].y * m1[r].y + m1[r].z * m1[r].z + m1[r].w * m1[r].w;
            dot = wave_bfly_sum(dot);
            nsq = wave_bfly_sum(nsq);
            float z = beta * dot / (knorm * sqrtf(nsq) + 1e-16f);
            float ez = expf(z - beta);   // z <= beta: exact max-shift, exponent <= 0
            if (lane == 0) EZ[row0 + r] = ez;
            wsum += ez;                  // identical across lanes
        }
        __syncthreads();                 // sblk reuse hazard vs phase A
        if (lane == 0) sblk[wid] = wsum;
        __syncthreads();
        if (t == 0) PART1[blockIdx.x] = sblk[0] + sblk[1] + sblk[2] + sblk[3];
    }
    grid.sync();

    // ---- Phase C (blocks 0..63): wc -> wg -> 3-tap circular shift -> wp; PART2 ----
    if (blockIdx.x < 64) {
        float v = 0.f;
        #pragma unroll
        for (int j = 0; j < 16; j++) v += PART1[lane + j * 64];
        float inv1 = 1.f / wave_bfly_sum(v);
        float g = 1.f / (1.f + expf(-O[MD + 1]));
        float s0r = O[MD + 2], s1r = O[MD + 3], s2r = O[MD + 4];
        float m = fmaxf(s0r, fmaxf(s1r, s2r));
        float e0 = expf(s0r - m), e1 = expf(s1r - m), e2 = expf(s2r - m);
        float inv_se = 1.f / (e0 + e1 + e2);
        float s0 = e0 * inv_se, s1 = e1 * inv_se, s2 = e2 * inv_se;
        float gamma = 1.f + softplus_f(O[MD + 5]);
        float gm1 = 1.f - g;
        int i = blockIdx.x * 256 + t;
        int im = (i == 0) ? (N - 1) : (i - 1);
        int ip = (i == N - 1) ? 0 : (i + 1);
        float wgm = g * EZ[im] * inv1 + gm1 * wprev[im];
        float wgc = g * EZ[i]  * inv1 + gm1 * wprev[i];
        float wgp = g * EZ[ip] * inv1 + gm1 * wprev[ip];
        float wsv = s0 * wgm + s1 * wgc + s2 * wgp;
        float wp = exp2f(gamma * log2f(wsv + 1e-16f));  // ws >= 0 always
        WP[i] = wp;
        float bs = wave_bfly_sum(wp);
        __syncthreads();
        if (lane == 0) sblk[wid] = bs;
        __syncthreads();
        if (t == 0) PART2[blockIdx.x] = sblk[0] + sblk[1] + sblk[2] + sblk[3];
    }
    grid.sync();

    // ---- Phase D: w = WP/SUM2 -> wout; new_mem = mem*(1 - w e) + w a ----
    {
        float inv2 = 1.f / wave_bfly_sum(PART2[lane]);  // exactly 64 entries
        const float4* m4 = (const float4*)mem;
        const float4* e4 = (const float4*)E;
        const float4* a4 = (const float4*)A;
        float4* o4 = (float4*)outMem;
        #pragma unroll
        for (int it = 0; it < (N * (MD / 4)) / (NBLK * NTHR); it++) {
            int idx = it * (NBLK * NTHR) + blockIdx.x * NTHR + t;
            int i = idx >> 7;
            int c = idx & 127;
            float wi = WP[i] * inv2;
            if (c == 0) wout[i] = wi;
            float4 mv = m4[idx];
            float4 e = e4[c];
            float4 a = a4[c];
            float4 o;
            o.x = mv.x * (1.f - wi * e.x) + wi * a.x;
            o.y = mv.y * (1.f - wi * e.y) + wi * a.y;
            o.z = mv.z * (1.f - wi * e.z) + wi * a.z;
            o.w = mv.w * (1.f - wi * e.w) + wi * a.w;
            o4[idx] = o;
        }
    }
}

extern "C" void kernel_launch(void* const* d_in, const int* in_sizes, int n_in,
                              void* d_out, int out_size, void* d_ws, size_t ws_size,
                              hipStream_t stream) {
    const float* emb   = (const float*)d_in[0];
    const float* wprev = (const float*)d_in[1];
    const float* mem   = (const float*)d_in[2];
    const float* W     = (const float*)d_in[3];
    const float* b     = (const float*)d_in[4];
    float* wout   = (float*)d_out;
    float* outMem = wout + N;
    float* wsf    = (float*)d_ws;

    void* args[] = {(void*)&emb, (void*)&wprev, (void*)&mem, (void*)&W,
                    (void*)&b, (void*)&wout, (void*)&outMem, (void*)&wsf};
    hipLaunchCooperativeKernel((void*)k_fused, dim3(NBLK), dim3(NTHR),
                               args, 0, stream);
}

// Round 5
// 110.967 us; speedup vs baseline: 3.4708x; 3.4708x over previous
//
#include <hip/hip_runtime.h>
#include <math.h>

#define N 16384
#define MD 512
#define CTRLDIM 1024
#define OUTF 1542  // 3*512+6

// ws layout (floats):
//   [0    .. 1541]   O      projection output o
//   [1552 .. 2063]   E      erase vec (16B-aligned)
//   [2064 .. 2575]   A      add vec (16B-aligned)
//   [2576 .. 3087]   PART1  per-block partial sums of exp (k_sim, 512 blocks)
//   [3600 .. 3663]   PART2  per-block partial sums of wp (k_shift, 64 blocks)
//   [3664 .. 20047]  EZ     exp(beta*sim - beta) per row
//   [20048.. 36431]  WP     (ws+eps)^gamma per row
// No atomics, no grid.sync (both measured catastrophic on this chip:
// R2 same-address atomics ~14ns each serialized; R4 grid.sync ~88us each).
// Partials to private slots; consumers reduce redundantly per-wave.

__device__ __forceinline__ float softplus_f(float x) {
    return (x > 20.f) ? x : log1pf(expf(x));
}

__device__ __forceinline__ float wave_bfly_sum(float v) {
    #pragma unroll
    for (int off = 1; off < 64; off <<= 1) v += __shfl_xor(v, off, 64);
    return v;
}

// o[row] = dot(W[row,:], emb) + b[row]; rows >= 518 also scatter into aligned E/A
__global__ void k_proj(const float* __restrict__ emb, const float* __restrict__ W,
                       const float* __restrict__ b, float* __restrict__ O,
                       float* __restrict__ E, float* __restrict__ A) {
    int row = blockIdx.x;
    int t = threadIdx.x;
    const float4* w4 = (const float4*)(W + (size_t)row * CTRLDIM);
    const float4* e4 = (const float4*)emb;
    float4 wv = w4[t];
    float4 ev = e4[t];
    float p = wv.x * ev.x + wv.y * ev.y + wv.z * ev.z + wv.w * ev.w;
    p = wave_bfly_sum(p);
    __shared__ float s[4];
    int lane = t & 63, wid = t >> 6;
    if (lane == 0) s[wid] = p;
    __syncthreads();
    if (t == 0) {
        float val = s[0] + s[1] + s[2] + s[3] + b[row];
        O[row] = val;
        if (row >= MD + 6 && row < 2 * MD + 6)      E[row - (MD + 6)] = val;
        else if (row >= 2 * MD + 6)                 A[row - (2 * MD + 6)] = val;
    }
}

// wave per 8 rows: EZ[row] = exp(beta*sim - beta); block partial -> PART1[blk]
// (sim <= 1 so exponent <= 0: softmax max-shift by beta is exact & free)
__global__ void __launch_bounds__(256) k_sim(const float* __restrict__ mem,
                                             const float* __restrict__ O,
                                             float* __restrict__ EZ,
                                             float* __restrict__ PART1) {
    int t = threadIdx.x, lane = t & 63, wid = t >> 6;
    const float4* k4 = (const float4*)O;
    float4 k0 = k4[lane], k1 = k4[lane + 64];
    float ksq = k0.x * k0.x + k0.y * k0.y + k0.z * k0.z + k0.w * k0.w
              + k1.x * k1.x + k1.y * k1.y + k1.z * k1.z + k1.w * k1.w;
    ksq = wave_bfly_sum(ksq);
    float knorm = sqrtf(ksq);
    float beta = softplus_f(O[MD]);
    int row0 = (blockIdx.x * 4 + wid) * 8;   // 512 blocks * 4 waves * 8 rows = 16384
    float4 m0[8], m1[8];
    #pragma unroll
    for (int r = 0; r < 8; r++) {
        const float4* m4 = (const float4*)(mem + (size_t)(row0 + r) * MD);
        m0[r] = m4[lane];
        m1[r] = m4[lane + 64];
    }
    float wsum = 0.f;
    #pragma unroll
    for (int r = 0; r < 8; r++) {
        float dot = m0[r].x * k0.x + m0[r].y * k0.y + m0[r].z * k0.z + m0[r].w * k0.w
                  + m1[r].x * k1.x + m1[r].y * k1.y + m1[r].z * k1.z + m1[r].w * k1.w;
        float nsq = m0[r].x * m0[r].x + m0[r].y * m0[r].y + m0[r].z * m0[r].z + m0[r].w * m0[r].w
                  + m1[r].x * m1[r].x + m1[r].y * m1[r].y + m1[r].z * m1[r].z + m1[r].w * m1[r].w;
        dot = wave_bfly_sum(dot);
        nsq = wave_bfly_sum(nsq);
        float z = beta * dot / (knorm * sqrtf(nsq) + 1e-16f);
        float ez = expf(z - beta);
        if (lane == r) EZ[row0 + r] = ez;   // spread the 8 stores across lanes 0..7
        wsum += ez;                          // identical across lanes
    }
    __shared__ float sblk[4];
    if (lane == 0) sblk[wid] = wsum;
    __syncthreads();
    if (t == 0) PART1[blockIdx.x] = sblk[0] + sblk[1] + sblk[2] + sblk[3];
}

// grid-wide: SUM1 from PART1 (per-wave redundant reduce) -> wc -> wg ->
// circular 3-tap shift -> wp=(ws+eps)^gamma -> PART2[blk]
__global__ void __launch_bounds__(256) k_shift(const float* __restrict__ EZ,
                                               const float* __restrict__ wprev,
                                               const float* __restrict__ O,
                                               const float* __restrict__ PART1,
                                               float* __restrict__ WP,
                                               float* __restrict__ PART2) {
    int t = threadIdx.x, lane = t & 63, wid = t >> 6;
    float v = 0.f;
    #pragma unroll
    for (int j = 0; j < 8; j++) v += PART1[lane + j * 64];   // 512 partials
    float inv1 = 1.f / wave_bfly_sum(v);
    // uniform scalars, recomputed per thread (cheap transcendentals)
    float g = 1.f / (1.f + expf(-O[MD + 1]));
    float s0r = O[MD + 2], s1r = O[MD + 3], s2r = O[MD + 4];
    float m = fmaxf(s0r, fmaxf(s1r, s2r));
    float e0 = expf(s0r - m), e1 = expf(s1r - m), e2 = expf(s2r - m);
    float inv_se = 1.f / (e0 + e1 + e2);
    float s0 = e0 * inv_se, s1 = e1 * inv_se, s2 = e2 * inv_se;
    float gamma = 1.f + softplus_f(O[MD + 5]);
    float gm1 = 1.f - g;
    int i = blockIdx.x * 256 + t;
    int im = (i == 0) ? (N - 1) : (i - 1);
    int ip = (i == N - 1) ? 0 : (i + 1);
    float wgm = g * EZ[im] * inv1 + gm1 * wprev[im];
    float wgc = g * EZ[i]  * inv1 + gm1 * wprev[i];
    float wgp = g * EZ[ip] * inv1 + gm1 * wprev[ip];
    float wsv = s0 * wgm + s1 * wgc + s2 * wgp;
    float wp = exp2f(gamma * log2f(wsv + 1e-16f));  // ws >= 0 always
    WP[i] = wp;
    float bs = wave_bfly_sum(wp);
    __shared__ float sblk[4];
    if (lane == 0) sblk[wid] = bs;
    __syncthreads();
    if (t == 0) PART2[blockIdx.x] = sblk[0] + sblk[1] + sblk[2] + sblk[3];
}

// SUM2 from PART2 (per-wave reduce); w = WP/SUM2 -> out;
// new_memory = memory * (1 - w_i*e_j) + w_i*a_j   (2 float4 per thread)
__global__ void __launch_bounds__(256) k_upd(const float* __restrict__ mem,
                                             const float* __restrict__ WP,
                                             const float* __restrict__ PART2,
                                             const float* __restrict__ E,
                                             const float* __restrict__ A,
                                             float* __restrict__ wout,
                                             float* __restrict__ outMem) {
    int t = threadIdx.x, lane = t & 63;
    float inv2 = 1.f / wave_bfly_sum(PART2[lane]);  // exactly 64 entries
    const float4* m4 = (const float4*)mem;
    const float4* e4 = (const float4*)E;
    const float4* a4 = (const float4*)A;
    float4* o4 = (float4*)outMem;
    #pragma unroll
    for (int it = 0; it < 2; it++) {
        int idx = (blockIdx.x * 2 + it) * 256 + t;  // float4 units
        int i = idx >> 7;
        int c = idx & 127;
        float wi = WP[i] * inv2;
        if (c == 0) wout[i] = wi;
        float4 mv = m4[idx];
        float4 e = e4[c];
        float4 a = a4[c];
        float4 o;
        o.x = mv.x * (1.f - wi * e.x) + wi * a.x;
        o.y = mv.y * (1.f - wi * e.y) + wi * a.y;
        o.z = mv.z * (1.f - wi * e.z) + wi * a.z;
        o.w = mv.w * (1.f - wi * e.w) + wi * a.w;
        o4[idx] = o;
    }
}

extern "C" void kernel_launch(void* const* d_in, const int* in_sizes, int n_in,
                              void* d_out, int out_size, void* d_ws, size_t ws_size,
                              hipStream_t stream) {
    const float* emb   = (const float*)d_in[0];
    const float* wprev = (const float*)d_in[1];
    const float* mem   = (const float*)d_in[2];
    const float* W     = (const float*)d_in[3];
    const float* b     = (const float*)d_in[4];
    float* out = (float*)d_out;
    float* wsf = (float*)d_ws;
    float* O     = wsf;
    float* E     = wsf + 1552;
    float* A     = wsf + 2064;
    float* PART1 = wsf + 2576;
    float* PART2 = wsf + 3600;
    float* EZ    = wsf + 3664;
    float* WP    = wsf + 20048;

    k_proj<<<OUTF, 256, 0, stream>>>(emb, W, b, O, E, A);
    k_sim<<<N / 32, 256, 0, stream>>>(mem, O, EZ, PART1);                  // 512 blocks
    k_shift<<<N / 256, 256, 0, stream>>>(EZ, wprev, O, PART1, WP, PART2);  // 64 blocks
    k_upd<<<(N * (MD / 4)) / 512, 256, 0, stream>>>(mem, WP, PART2, E, A, out, out + N);
}